// Round 4
// baseline (134.544 us; speedup 1.0000x reference)
//
#include <hip/hip_runtime.h>
#include <math.h>

// Cox partial likelihood NLL.
// loss = -(1/n) * sum_i e_i * (risk_i - log(P[time_i]))
//   where P[t] = sum_{t' <= t} S[t'],  S[t] = sum_{time_j = t} exp(risk_j)
// Decompose: A = sum_i e_i*risk_i ; B = sum_t E[t]*log(P[t]), E[t] = sum_{time_j=t} e_j
// loss = -(A - B)/n
//
// R4: ONE window per block (grid 8192), removing the 4x serial window chain
// per wave (R1-R3 all plateaued ~65-90us with idle pipes -> latency-bound on
// the per-wave serial chain, not on any pipe).

#define TMAXV   100000
#define NPAD    100352          // 98 * 1024, padded bucket count
#define NBLK_SC 98
#define VPT     8               // elements per thread
#define SENT    0x7fffffff      // sentinel time for invalid lanes (never flushed)

__device__ __forceinline__ void atomAddF(float* p, float v) {
    unsafeAtomicAdd(p, v);      // native global_atomic_add_f32
}

// Block reduce (up to 16 waves). Result valid in lane 0 of wave 0 only.
__device__ __forceinline__ float block_reduce_sum(float v, float* lds) {
    const int lane = threadIdx.x & 63;
    const int wid  = threadIdx.x >> 6;
    #pragma unroll
    for (int d = 32; d > 0; d >>= 1) v += __shfl_down(v, d);
    __syncthreads();
    if (lane == 0) lds[wid] = v;
    __syncthreads();
    float r = 0.f;
    if (wid == 0) {
        const int nw = (int)(blockDim.x >> 6);
        r = (lane < nw) ? lds[lane] : 0.f;
        #pragma unroll
        for (int d = 8; d > 0; d >>= 1) r += __shfl_down(r, d);
    }
    return r;
}

__global__ __launch_bounds__(256)
void k1_bucket(const float* __restrict__ risk, const float* __restrict__ ev,
               const int* __restrict__ tim,
               float* __restrict__ S, float* __restrict__ E,
               float* __restrict__ A, int n) {
    __shared__ float lds[16];
    const int lane = threadIdx.x & 63;
    const int base = ((int)blockIdx.x * (int)blockDim.x + (int)threadIdx.x) * VPT;

    float r[VPT], w[VPT];
    int   t[VPT];
    if (base + VPT <= n) {
        const float4 ra = *(const float4*)(risk + base);
        const float4 rb = *(const float4*)(risk + base + 4);
        const float4 wa = *(const float4*)(ev + base);
        const float4 wb = *(const float4*)(ev + base + 4);
        const int4   ta = *(const int4*)(tim + base);
        const int4   tb = *(const int4*)(tim + base + 4);
        r[0]=ra.x; r[1]=ra.y; r[2]=ra.z; r[3]=ra.w;
        r[4]=rb.x; r[5]=rb.y; r[6]=rb.z; r[7]=rb.w;
        w[0]=wa.x; w[1]=wa.y; w[2]=wa.z; w[3]=wa.w;
        w[4]=wb.x; w[5]=wb.y; w[6]=wb.z; w[7]=wb.w;
        t[0]=ta.x; t[1]=ta.y; t[2]=ta.z; t[3]=ta.w;
        t[4]=tb.x; t[5]=tb.y; t[6]=tb.z; t[7]=tb.w;
    } else {
        #pragma unroll
        for (int j = 0; j < VPT; ++j) {
            const int i = base + j;
            const bool ok = (i < n);
            r[j] = ok ? risk[i] : 0.f;
            w[j] = ok ? ev[i]   : 0.f;
            t[j] = ok ? tim[i]  : SENT;
        }
    }

    float ve[VPT];
    float accA = 0.f;
    #pragma unroll
    for (int j = 0; j < VPT; ++j) {
        ve[j] = __expf(r[j]);
        accA += w[j] * r[j];              // w==0 for invalid lanes
    }

    // trailing-run sums (times sorted => equality to tail is contiguous)
    const int head_t = t[0];
    const int tail_t = t[VPT - 1];
    float tsv = 0.f, tsw = 0.f;
    #pragma unroll
    for (int j = 0; j < VPT; ++j) {
        if (t[j] == tail_t) { tsv += ve[j]; tsw += w[j]; }
    }

    // cross-lane segmented inclusive scan of trailing sums, keyed on tail_t
    float Sv = tsv, Sw = tsw;
    #pragma unroll
    for (int d = 1; d < 64; d <<= 1) {
        const float ov = __shfl_up(Sv, d);
        const float ow = __shfl_up(Sw, d);
        const int   ok = __shfl_up(tail_t, d);
        if (lane >= d && ok == tail_t) { Sv += ov; Sw += ow; }
    }

    // carry into this thread's head run (exact under sortedness)
    float cv = 0.f, cw = 0.f;
    {
        const float pv = __shfl_up(Sv, 1);
        const float pw = __shfl_up(Sw, 1);
        const int   pk = __shfl_up(tail_t, 1);
        if (lane > 0 && pk == head_t) { cv = pv; cw = pw; }
    }

    // per-thread sequential run pass, flushing closed runs
    int   cur_t = head_t;
    float cur_v = cv, cur_w = cw;
    #pragma unroll
    for (int j = 0; j < VPT; ++j) {
        if (t[j] != cur_t) {
            if (cur_t != SENT) {
                atomAddF(&S[cur_t], cur_v);
                atomAddF(&E[cur_t], cur_w);
            }
            cur_t = t[j]; cur_v = 0.f; cur_w = 0.f;
        }
        cur_v += ve[j]; cur_w += w[j];
    }
    // trailing run: flush only if it does not continue into the next lane
    const int nh = __shfl_down(head_t, 1);
    if ((lane == 63 || nh != tail_t) && cur_t != SENT) {
        atomAddF(&S[cur_t], cur_v);
        atomAddF(&E[cur_t], cur_w);
    }

    const float tot = block_reduce_sum(accA, lds);
    if (threadIdx.x == 0) atomAddF(A, tot);
}

// K2: per-1024-chunk partial sums of S.
__global__ __launch_bounds__(256)
void k2_partials(const float* __restrict__ S, float* __restrict__ partials) {
    __shared__ float lds[16];
    const int base = (int)blockIdx.x * 1024;
    float v = 0.f;
    for (int j = (int)threadIdx.x; j < 1024; j += 256) v += S[base + j];
    const float tot = block_reduce_sum(v, lds);
    if (threadIdx.x == 0) partials[blockIdx.x] = tot;
}

// K3: per-chunk inclusive scan of S (+offset), dot with E via log(P) -> B.
__global__ __launch_bounds__(1024)
void k3_scan_dot(const float* __restrict__ S, const float* __restrict__ E,
                 const float* __restrict__ partials, float* __restrict__ Bacc) {
    __shared__ float lds[16];
    __shared__ float wsum[16];
    __shared__ float s_off;
    const int tid  = (int)threadIdx.x;
    const int lane = tid & 63;
    const int wid  = tid >> 6;
    const int base = (int)blockIdx.x * 1024;

    float p = (tid < (int)blockIdx.x) ? partials[tid] : 0.f;
    const float off = block_reduce_sum(p, lds);
    if (tid == 0) s_off = off;
    __syncthreads();
    const float offset = s_off;

    const float x = S[base + tid];
    float s = x;
    #pragma unroll
    for (int d = 1; d < 64; d <<= 1) {
        const float o = __shfl_up(s, d);
        if (lane >= d) s += o;
    }
    if (lane == 63) wsum[wid] = s;
    __syncthreads();
    if (wid == 0) {
        float ws = (lane < 16) ? wsum[lane] : 0.f;
        #pragma unroll
        for (int d = 1; d < 16; d <<= 1) {
            const float o = __shfl_up(ws, d);
            if (lane >= d) ws += o;
        }
        if (lane < 16) wsum[lane] = ws;
    }
    __syncthreads();
    const float incl = s + (wid > 0 ? wsum[wid - 1] : 0.f);
    const float P = offset + incl;

    const float w = E[base + tid];
    const float c = (w != 0.f) ? w * __logf(P) : 0.f;
    const float tot = block_reduce_sum(c, lds);
    if (tid == 0) atomAddF(Bacc, tot);
}

__global__ void k4_final(const float* __restrict__ A, const float* __restrict__ B,
                         float* __restrict__ out, float inv_n) {
    out[0] = -(A[0] - B[0]) * inv_n;
}

extern "C" void kernel_launch(void* const* d_in, const int* in_sizes, int n_in,
                              void* d_out, int out_size, void* d_ws, size_t ws_size,
                              hipStream_t stream) {
    const float* risk = (const float*)d_in[0];
    const float* ev   = (const float*)d_in[1];
    const int*   tim  = (const int*)d_in[2];
    float* out = (float*)d_out;
    const int n = in_sizes[0];

    // workspace layout (floats): S[NPAD] | E[NPAD] | partials[128] | A | B
    float* S        = (float*)d_ws;
    float* E        = S + NPAD;
    float* partials = E + NPAD;
    float* A        = partials + 128;
    float* B        = A + 1;

    hipMemsetAsync(d_ws, 0, (size_t)(2 * NPAD + 130) * sizeof(float), stream);

    const int threads = 256;
    const int elems_per_block = threads * VPT;                 // 2048
    const int blocks = (n + elems_per_block - 1) / elems_per_block;  // 8192 for N=16.7M

    hipLaunchKernelGGL(k1_bucket, dim3(blocks), dim3(threads), 0, stream,
                       risk, ev, tim, S, E, A, n);
    hipLaunchKernelGGL(k2_partials, dim3(NBLK_SC), dim3(256), 0, stream, S, partials);
    hipLaunchKernelGGL(k3_scan_dot, dim3(NBLK_SC), dim3(1024), 0, stream, S, E, partials, B);
    hipLaunchKernelGGL(k4_final, dim3(1), dim3(1), 0, stream, A, B, out, 1.0f / (float)n);
}

// Round 5
// 55.152 us; speedup vs baseline: 2.4395x; 2.4395x over previous
//
#include <hip/hip_runtime.h>
#include <math.h>

// Cox partial likelihood NLL.
// loss = -(1/n) * sum_i e_i * (risk_i - log(P[time_i]))
//   where P[t] = sum_{t' <= t} S[t'],  S[t] = sum_{time_j = t} exp(risk_j)
// Decompose: A = sum_i e_i*risk_i ; B = sum_t E[t]*log(P[t]), E[t] = sum_{time_j=t} e_j
// loss = -(A - B)/n
//
// R5: (a) accA -> per-block partial store (no same-address global atomic --
// R4 showed +4x blocks => +46us, implicating the hot A line at the MALL);
// (b) VPT 8->16: halves the dependent ds_bpermute scan chains per wave and
// doubles bytes in flight. Window logic otherwise identical to R2/R3.

#define TMAXV   100000
#define NPAD    100352          // 98 * 1024, padded bucket count
#define NBLK_SC 98
#define VPT     16              // elements per thread per window
#define NBLK1   2048
#define SENT    0x7fffffff      // sentinel time for invalid lanes (never flushed)

__device__ __forceinline__ void atomAddF(float* p, float v) {
    unsafeAtomicAdd(p, v);      // native global_atomic_add_f32
}

// Block reduce (up to 16 waves). Result valid in lane 0 of wave 0 only.
__device__ __forceinline__ float block_reduce_sum(float v, float* lds) {
    const int lane = threadIdx.x & 63;
    const int wid  = threadIdx.x >> 6;
    #pragma unroll
    for (int d = 32; d > 0; d >>= 1) v += __shfl_down(v, d);
    __syncthreads();
    if (lane == 0) lds[wid] = v;
    __syncthreads();
    float r = 0.f;
    if (wid == 0) {
        const int nw = (int)(blockDim.x >> 6);
        r = (lane < nw) ? lds[lane] : 0.f;
        #pragma unroll
        for (int d = 8; d > 0; d >>= 1) r += __shfl_down(r, d);
    }
    return r;
}

__global__ __launch_bounds__(256)
void k1_bucket(const float* __restrict__ risk, const float* __restrict__ ev,
               const int* __restrict__ tim,
               float* __restrict__ S, float* __restrict__ E,
               float* __restrict__ Apart, int n, int per_block) {
    __shared__ float lds[16];
    const int lane  = threadIdx.x & 63;
    const int start = (int)blockIdx.x * per_block;
    int end = start + per_block;
    if (end > n) end = n;
    const int step = (int)blockDim.x * VPT;

    float accA = 0.f;
    for (int i0 = start; i0 < end; i0 += step) {
        const int base = i0 + (int)threadIdx.x * VPT;  // this thread's strip
        float r[VPT], w[VPT];
        int   t[VPT];
        if (base + VPT <= end) {
            #pragma unroll
            for (int q = 0; q < VPT / 4; ++q) {
                const float4 rr = *(const float4*)(risk + base + 4 * q);
                const float4 ww = *(const float4*)(ev   + base + 4 * q);
                const int4   tt = *(const int4*)(tim   + base + 4 * q);
                r[4*q+0]=rr.x; r[4*q+1]=rr.y; r[4*q+2]=rr.z; r[4*q+3]=rr.w;
                w[4*q+0]=ww.x; w[4*q+1]=ww.y; w[4*q+2]=ww.z; w[4*q+3]=ww.w;
                t[4*q+0]=tt.x; t[4*q+1]=tt.y; t[4*q+2]=tt.z; t[4*q+3]=tt.w;
            }
        } else {
            #pragma unroll
            for (int j = 0; j < VPT; ++j) {
                const int i = base + j;
                const bool ok = (i < end);
                r[j] = ok ? risk[i] : 0.f;
                w[j] = ok ? ev[i]   : 0.f;
                t[j] = ok ? tim[i]  : SENT;
            }
        }

        float ve[VPT];
        #pragma unroll
        for (int j = 0; j < VPT; ++j) {
            ve[j] = __expf(r[j]);
            accA += w[j] * r[j];          // w==0 for invalid lanes
        }

        // trailing-run sums (times sorted => equality to tail is contiguous)
        const int head_t = t[0];
        const int tail_t = t[VPT - 1];
        float tsv = 0.f, tsw = 0.f;
        #pragma unroll
        for (int j = 0; j < VPT; ++j) {
            if (t[j] == tail_t) { tsv += ve[j]; tsw += w[j]; }
        }

        // cross-lane segmented inclusive scan of trailing sums, keyed on tail_t
        float Sv = tsv, Sw = tsw;
        #pragma unroll
        for (int d = 1; d < 64; d <<= 1) {
            const float ov = __shfl_up(Sv, d);
            const float ow = __shfl_up(Sw, d);
            const int   ok = __shfl_up(tail_t, d);
            if (lane >= d && ok == tail_t) { Sv += ov; Sw += ow; }
        }

        // carry into this thread's head run (exact under sortedness)
        float cv = 0.f, cw = 0.f;
        {
            const float pv = __shfl_up(Sv, 1);
            const float pw = __shfl_up(Sw, 1);
            const int   pk = __shfl_up(tail_t, 1);
            if (lane > 0 && pk == head_t) { cv = pv; cw = pw; }
        }

        // per-thread sequential run pass, flushing closed runs
        int   cur_t = head_t;
        float cur_v = cv, cur_w = cw;
        #pragma unroll
        for (int j = 0; j < VPT; ++j) {
            if (t[j] != cur_t) {
                if (cur_t != SENT) {
                    atomAddF(&S[cur_t], cur_v);
                    atomAddF(&E[cur_t], cur_w);
                }
                cur_t = t[j]; cur_v = 0.f; cur_w = 0.f;
            }
            cur_v += ve[j]; cur_w += w[j];
        }
        // trailing run: flush only if it does not continue into the next lane
        const int nh = __shfl_down(head_t, 1);
        if ((lane == 63 || nh != tail_t) && cur_t != SENT) {
            atomAddF(&S[cur_t], cur_v);
            atomAddF(&E[cur_t], cur_w);
        }
    }

    const float tot = block_reduce_sum(accA, lds);
    if (threadIdx.x == 0) Apart[blockIdx.x] = tot;   // plain store, no hot line
}

// K2: per-1024-chunk partial sums of S.
__global__ __launch_bounds__(256)
void k2_partials(const float* __restrict__ S, float* __restrict__ partials) {
    __shared__ float lds[16];
    const int base = (int)blockIdx.x * 1024;
    float v = 0.f;
    for (int j = (int)threadIdx.x; j < 1024; j += 256) v += S[base + j];
    const float tot = block_reduce_sum(v, lds);
    if (threadIdx.x == 0) partials[blockIdx.x] = tot;
}

// K3: per-chunk inclusive scan of S (+offset), dot with E via log(P) -> B.
__global__ __launch_bounds__(1024)
void k3_scan_dot(const float* __restrict__ S, const float* __restrict__ E,
                 const float* __restrict__ partials, float* __restrict__ Bacc) {
    __shared__ float lds[16];
    __shared__ float wsum[16];
    __shared__ float s_off;
    const int tid  = (int)threadIdx.x;
    const int lane = tid & 63;
    const int wid  = tid >> 6;
    const int base = (int)blockIdx.x * 1024;

    float p = (tid < (int)blockIdx.x) ? partials[tid] : 0.f;
    const float off = block_reduce_sum(p, lds);
    if (tid == 0) s_off = off;
    __syncthreads();
    const float offset = s_off;

    const float x = S[base + tid];
    float s = x;
    #pragma unroll
    for (int d = 1; d < 64; d <<= 1) {
        const float o = __shfl_up(s, d);
        if (lane >= d) s += o;
    }
    if (lane == 63) wsum[wid] = s;
    __syncthreads();
    if (wid == 0) {
        float ws = (lane < 16) ? wsum[lane] : 0.f;
        #pragma unroll
        for (int d = 1; d < 16; d <<= 1) {
            const float o = __shfl_up(ws, d);
            if (lane >= d) ws += o;
        }
        if (lane < 16) wsum[lane] = ws;
    }
    __syncthreads();
    const float incl = s + (wid > 0 ? wsum[wid - 1] : 0.f);
    const float P = offset + incl;

    const float w = E[base + tid];
    const float c = (w != 0.f) ? w * __logf(P) : 0.f;
    const float tot = block_reduce_sum(c, lds);
    if (tid == 0) atomAddF(Bacc, tot);
}

// K4: reduce Apart[NBLK1], combine with B, write loss.
__global__ __launch_bounds__(256)
void k4_final(const float* __restrict__ Apart, const float* __restrict__ B,
              float* __restrict__ out, float inv_n) {
    __shared__ float lds[16];
    float v = 0.f;
    for (int j = (int)threadIdx.x; j < NBLK1; j += 256) v += Apart[j];
    const float tot = block_reduce_sum(v, lds);
    if (threadIdx.x == 0) out[0] = -(tot - B[0]) * inv_n;
}

extern "C" void kernel_launch(void* const* d_in, const int* in_sizes, int n_in,
                              void* d_out, int out_size, void* d_ws, size_t ws_size,
                              hipStream_t stream) {
    const float* risk = (const float*)d_in[0];
    const float* ev   = (const float*)d_in[1];
    const int*   tim  = (const int*)d_in[2];
    float* out = (float*)d_out;
    const int n = in_sizes[0];

    // workspace layout (floats): S[NPAD] | E[NPAD] | partials[128] | Apart[NBLK1] | B
    float* S        = (float*)d_ws;
    float* E        = S + NPAD;
    float* partials = E + NPAD;
    float* Apart    = partials + 128;
    float* B        = Apart + NBLK1;

    hipMemsetAsync(d_ws, 0, (size_t)(2 * NPAD + 128 + NBLK1 + 2) * sizeof(float), stream);

    const int threads = 256;
    const int win = threads * VPT;                     // 4096 elements per block-iter
    int per_block = (n + NBLK1 - 1) / NBLK1;
    per_block = ((per_block + win - 1) / win) * win;   // window-aligned (8192 for N=16.7M)

    hipLaunchKernelGGL(k1_bucket, dim3(NBLK1), dim3(threads), 0, stream,
                       risk, ev, tim, S, E, Apart, n, per_block);
    hipLaunchKernelGGL(k2_partials, dim3(NBLK_SC), dim3(256), 0, stream, S, partials);
    hipLaunchKernelGGL(k3_scan_dot, dim3(NBLK_SC), dim3(1024), 0, stream, S, E, partials, B);
    hipLaunchKernelGGL(k4_final, dim3(1), dim3(256), 0, stream, Apart, B, out, 1.0f / (float)n);
}